// Round 7
// baseline (173.661 us; speedup 1.0000x reference)
//
#include <hip/hip_runtime.h>
#include <cstdint>
#include <cstddef>

typedef unsigned long long u64;
typedef unsigned int u32;
typedef unsigned short u16;

#define N_ 4096
#define MMAX_ 2048   // max candidates per (b,c) pair; actual ~1365
#define KCAP_ 32     // pred-list cap; geometric ball bound => max deg ~27
#define SENT_ 2048   // sentinel pred index -> always-dead byte slot

__device__ __forceinline__ float sigf(float x) { return 1.0f / (1.0f + expf(-x)); }

// any-of-4 alive check; w? are u32s holding two u16 indices each (constant reg idx)
#define ANY4(arr, wa, wb) \
  ((int)((arr)[(wa) & 0xFFFFu] | (arr)[(wa) >> 16] | \
         (arr)[(wb) & 0xFFFFu] | (arr)[(wb) >> 16]))
// degree-bounded group scan over reg-resident pred list (groups of 4, sentinel-padded)
#define GRPSCAN(arr, dw, dg, outAny) do { \
  outAny = ANY4(arr, dw[0], dw[1]); \
  if ((dg) > 4) { outAny |= ANY4(arr, dw[2], dw[3]); \
  if ((dg) > 8) { outAny |= ANY4(arr, dw[4], dw[5]); \
  if ((dg) > 12) { outAny |= ANY4(arr, dw[6], dw[7]); \
  if ((dg) > 16) { outAny |= ANY4(arr, dw[8], dw[9]); \
  if ((dg) > 20) { outAny |= ANY4(arr, dw[10], dw[11]); \
  if ((dg) > 24) { outAny |= ANY4(arr, dw[12], dw[13]); \
  if ((dg) > 28) { outAny |= ANY4(arr, dw[14], dw[15]); }}}}}}} \
} while (0)

// ---------------- K1: compact + dense lattice maps ----------------------------
// One block per (b,c) pair. Writes: slot-indexed positions sp4[slot], dense
// per-anchor posG[n]={x,y,z,bitcast(okey)} (invalid -> x=1e9 so distance test
// self-rejects) and slotG[n] (0xFFFF invalid). Sorted order is only needed to
// ORIENT conflict edges; okey comparison reproduces it exactly (see k_adj).
__global__ __launch_bounds__(1024) void k_compact(
    const float* __restrict__ pc, const float* __restrict__ pb,
    int* __restrict__ Mcnt, float4* __restrict__ posG, u16* __restrict__ slotG,
    float4* __restrict__ sp4) {
  int pair = blockIdx.x, b = pair >> 1, c = (pair & 1) + 1;
  int tid = threadIdx.x, lane = tid & 63;
  __shared__ int cnt;
  if (tid == 0) cnt = 0;
  __syncthreads();
  const float* pcb = pc + (size_t)b * 3 * N_;
  const float* pbb = pb + (size_t)b * 3 * N_;
  for (int base = 0; base < N_; base += 1024) {
    int n = base + tid;
    float v0 = pcb[n], v1 = pcb[n + N_], v2 = pcb[n + 2 * N_];
    float cf = v0; int a = 0;
    if (v1 > cf) { cf = v1; a = 1; }
    if (v2 > cf) { cf = v2; a = 2; }
    bool valid = (a == c);
    u32 o = __float_as_uint(cf);
    o ^= (o >> 31) ? 0xFFFFFFFFu : 0x80000000u;   // ascending-orderable conf
    u64 ball = __ballot(valid);
    int wbase = 0;
    if (lane == 0 && ball) wbase = atomicAdd(&cnt, __popcll(ball));
    wbase = __shfl(wbase, 0);
    int p = wbase + __popcll(ball & ((1ull << lane) - 1ull));
    if (valid && p < MMAX_) {
      float d = (float)(n >> 10), h = (float)((n >> 5) & 31), w = (float)(n & 31);
      // (g+s)/dims*REAL == (g+s)*{0.75,0.78125,0.78125} bit-exactly (pow2 dims)
      float x = (d + sigf(pbb[n])) * 0.75f;
      float y = (h + sigf(pbb[n + N_])) * 0.78125f;
      float z = (w + sigf(pbb[n + 2 * N_])) * 0.78125f;
      float4 vg; vg.x = x; vg.y = y; vg.z = z; vg.w = __uint_as_float(o);
      posG[pair * N_ + n] = vg;
      slotG[pair * N_ + n] = (u16)p;
      float4 vs; vs.x = x; vs.y = y; vs.z = z; vs.w = 0.f;
      sp4[pair * MMAX_ + p] = vs;
    } else {
      float4 vg; vg.x = 1e9f; vg.y = 1e9f; vg.z = 1e9f; vg.w = 0.f;
      posG[pair * N_ + n] = vg;
      slotG[pair * N_ + n] = (u16)0xFFFF;
    }
  }
  __syncthreads();
  if (tid == 0) {
    int M = cnt; if (M > MMAX_) M = MMAX_;
    Mcnt[pair] = M;
  }
}

// ---------------- K2: lattice-ball predecessor adjacency ----------------------
// One thread per anchor. Geometric pruning (offsets in open (0,1)):
//   cut=1.0 : two axes at |dcell|=2 give min d2 >= 1.17 > 1.0  -> 80-cell ball
//   cut=0.75: any axis at |dcell|=2 exceeds 0.75 strictly      -> 26-cell ball
// Independent coalesced 16B loads, fully unrolled -> pipelined, no LDS.
// pred(i,j): dist<cut && (okey_i > okey_j || (okey_i==okey_j && n_i < n_j))
// == "i earlier in ref's stable desc-conf sort" (key orientation, label-free).
template <int EXT>
__device__ __forceinline__ void adj_body(
    const float4* __restrict__ posG, const u16* __restrict__ slotG,
    int* __restrict__ deg, u16* __restrict__ predL, int pair, int n, int slot,
    float cut2) {
  float4 self = posG[pair * N_ + n];
  u32 okey = __float_as_uint(self.w);
  int d0 = n >> 10, h0 = (n >> 5) & 31, w0 = n & 31;
  u16* rowp = predL + (((size_t)pair * MMAX_ + slot) << 5);
  int cnt = 0;
  #pragma unroll
  for (int dd = -EXT; dd <= EXT; ++dd) {
    #pragma unroll
    for (int dh = -EXT; dh <= EXT; ++dh) {
      #pragma unroll
      for (int dw = -EXT; dw <= EXT; ++dw) {
        if (dd == 0 && dh == 0 && dw == 0) continue;
        // compile-time ball prune: at most one axis at |2|
        if ((dd * dd == 4) + (dh * dh == 4) + (dw * dw == 4) > 1) continue;
        int d2i = d0 + dd, h2i = h0 + dh, w2i = w0 + dw;
        if ((u32)d2i < 4u && (u32)h2i < 32u && (u32)w2i < 32u) {
          int n2 = (d2i << 10) | (h2i << 5) | w2i;
          float4 pn = posG[pair * N_ + n2];    // invalid -> 1e9 -> dist rejects
          float dx = pn.x - self.x, dy = pn.y - self.y, dz = pn.z - self.z;
          float dsq = dx * dx + dy * dy + dz * dz;
          u32 ok2 = __float_as_uint(pn.w);
          bool pred = (dsq < cut2) && (ok2 > okey || (ok2 == okey && n2 < n));
          if (pred) {                          // rare (~2 per row)
            u16 s2 = slotG[pair * N_ + n2];
            if (cnt < KCAP_) rowp[cnt] = s2;
            cnt++;
          }
        }
      }
    }
  }
  if (cnt > KCAP_) cnt = KCAP_;
  deg[pair * MMAX_ + slot] = cnt;
  int pad = (cnt + 3) & ~3;                    // pad group-of-4 with sentinel
  for (int s = cnt; s < pad; ++s) rowp[s] = (u16)SENT_;
}

__global__ __launch_bounds__(256) void k_adj(
    const float4* __restrict__ posG, const u16* __restrict__ slotG,
    int* __restrict__ deg, u16* __restrict__ predL) {
  int idx = blockIdx.x * 256 + threadIdx.x;   // 0..16383
  int pair = idx >> 12, n = idx & (N_ - 1);
  int slot = slotG[pair * N_ + n];
  if (slot == 0xFFFF) return;
  if (pair & 1) adj_body<1>(posG, slotG, deg, predL, pair, n, slot, 0.5625f);
  else          adj_body<2>(posG, slotG, deg, predL, pair, n, slot, 1.0f);
}

// ---------------- K3: byte-array LDS matrix-NMS fixpoint ----------------------
// Per-iteration exactly the ref update:
//   free_i  = alive_i && no alive conflicting predecessor
//   alive'_j = alive_j && no free conflicting predecessor
// Monotone => early break at fixpoint exact; capped at ref's 32 iters.
__global__ __launch_bounds__(1024) void k_nms(
    const int* __restrict__ Mcnt, const int* __restrict__ deg,
    const u16* __restrict__ predL, const float4* __restrict__ sp4,
    float4* __restrict__ aliveList, int* __restrict__ Acnt, int* __restrict__ out) {
  int pair = blockIdx.x;
  int tid = threadIdx.x;
  int M = Mcnt[pair];
  __shared__ unsigned char aliveB[2064];  // [2048] = sentinel slot, always 0
  __shared__ unsigned char freeB[2064];
  __shared__ int flag[2], acnt;
  int r0 = tid, r1 = tid + 1024;
  int dg0 = deg[pair * MMAX_ + r0];       // used only when r0 < M (else garbage, unused)
  int dg1 = deg[pair * MMAX_ + r1];
  u32 dw0[16], dw1[16];
  {
    const uint4* p0 = (const uint4*)(predL + (((size_t)pair * MMAX_ + r0) << 5));
    const uint4* p1 = (const uint4*)(predL + (((size_t)pair * MMAX_ + r1) << 5));
    #pragma unroll
    for (int q = 0; q < 4; ++q) {
      uint4 t0 = p0[q];
      dw0[4 * q] = t0.x; dw0[4 * q + 1] = t0.y; dw0[4 * q + 2] = t0.z; dw0[4 * q + 3] = t0.w;
      uint4 t1 = p1[q];
      dw1[4 * q] = t1.x; dw1[4 * q + 1] = t1.y; dw1[4 * q + 2] = t1.z; dw1[4 * q + 3] = t1.w;
    }
  }
  bool a0 = (r0 < M), a1 = (r1 < M);
  aliveB[r0] = a0; aliveB[r1] = a1;
  freeB[r0] = 0; freeB[r1] = 0;
  if (tid < 16) { aliveB[2048 + tid] = 0; freeB[2048 + tid] = 0; }
  if (tid == 0) { flag[0] = 0; flag[1] = 0; acnt = 0; }
  __syncthreads();

  for (int iter = 0; iter < 32; ++iter) {
    if (tid == 0) flag[(iter + 1) & 1] = 0;  // reset NEXT flag (barriers order it)
    // ---- stage 1: free = alive && all preds dead
    bool fr0 = a0, fr1 = a1;
    if (a0 && dg0) { int any; GRPSCAN(aliveB, dw0, dg0, any); fr0 = (any == 0); }
    if (a1 && dg1) { int any; GRPSCAN(aliveB, dw1, dg1, any); fr1 = (any == 0); }
    freeB[r0] = fr0; freeB[r1] = fr1;
    __syncthreads();
    // ---- stage 2: alive' = alive && no free pred (monotone: only 1->0)
    int lch = 0;
    if (a0 && dg0) { int any; GRPSCAN(freeB, dw0, dg0, any); if (any) { a0 = false; aliveB[r0] = 0; lch = 1; } }
    if (a1 && dg1) { int any; GRPSCAN(freeB, dw1, dg1, any); if (any) { a1 = false; aliveB[r1] = 0; lch = 1; } }
    if (lch) flag[iter & 1] = 1;
    __syncthreads();
    if (!flag[iter & 1]) break;  // fixpoint: remaining ref iterations are no-ops
  }

  // compact alive positions (order irrelevant for matching)
  {
    u64 ball = __ballot(a0);
    int base = 0;
    if ((tid & 63) == 0 && ball) base = atomicAdd(&acnt, __popcll(ball));
    base = __shfl(base, 0);
    if (a0) {
      int slot = base + __popcll(ball & ((1ull << (tid & 63)) - 1ull));
      aliveList[pair * MMAX_ + slot] = sp4[pair * MMAX_ + r0];
    }
  }
  {
    u64 ball = __ballot(a1);
    int base = 0;
    if ((tid & 63) == 0 && ball) base = atomicAdd(&acnt, __popcll(ball));
    base = __shfl(base, 0);
    if (a1) {
      int slot = base + __popcll(ball & ((1ull << (tid & 63)) - 1ull));
      aliveList[pair * MMAX_ + slot] = sp4[pair * MMAX_ + r1];
    }
  }
  __syncthreads();
  if (tid == 0) {
    int A = acnt;
    Acnt[pair] = A;
    out[pair * 3 + 0] = 0;   // tp  (K4 adds)
    out[pair * 3 + 1] = A;   // fp = A - tp (K4 subtracts)
    out[pair * 3 + 2] = 0;   // fn = t_cls - tp (K4 adds/subtracts)
  }
}

// ---------------- K4: target matching, global-direct alive scan ---------------
// 16 blocks per pair, one thread per raw anchor. aliveList (~9.6 KB/pair) is
// L1/L2-hot; wave-uniform global loads issue ~3x cheaper than ds_read_b128
// broadcast and need no staging barrier. Break-free -> loads pipeline.
__global__ __launch_bounds__(256) void k_match(
    const int* __restrict__ Acnt, const float4* __restrict__ aliveList,
    const int* __restrict__ tcls, const float* __restrict__ tb,
    int* __restrict__ out) {
  int pair = blockIdx.x >> 4, tblk = blockIdx.x & 15;
  int b = pair >> 1, c = (pair & 1) + 1;
  float cut2 = (pair & 1) ? 0.5625f : 1.0f;
  int A = Acnt[pair];
  __shared__ int s_tp, s_t;
  if (threadIdx.x == 0) { s_tp = 0; s_t = 0; }
  __syncthreads();
  int t = tblk * 256 + threadIdx.x;
  int isC = (tcls[b * N_ + t] == c) ? 1 : 0;
  float d = (float)(t >> 10), h = (float)((t >> 5) & 31), w = (float)(t & 31);
  const float* tbp = tb + ((size_t)b * N_ + t) * 3;
  float tx = (d + tbp[0]) * 0.75f;
  float ty = (h + tbp[1]) * 0.78125f;
  float tz = (w + tbp[2]) * 0.78125f;
  const float4* al = aliveList + (size_t)pair * MMAX_;
  int m = 0;
  #pragma unroll 4
  for (int a = 0; a < A; ++a) {
    float4 p = al[a];
    float dx = p.x - tx, dy = p.y - ty, dz = p.z - tz;
    m |= (int)(dx * dx + dy * dy + dz * dz < cut2);
  }
  m &= isC;
  atomicAdd(&s_tp, m);
  atomicAdd(&s_t, isC);
  __syncthreads();
  if (threadIdx.x == 0) {
    atomicAdd(&out[pair * 3 + 0], s_tp);
    atomicAdd(&out[pair * 3 + 1], -s_tp);
    atomicAdd(&out[pair * 3 + 2], s_t - s_tp);
  }
}

// ------------------------------------------------------------------------------
extern "C" void kernel_launch(void* const* d_in, const int* in_sizes, int n_in,
                              void* d_out, int out_size, void* d_ws, size_t ws_size,
                              hipStream_t stream) {
  (void)in_sizes; (void)n_in; (void)out_size; (void)ws_size;
  const float* pc = (const float*)d_in[0];  // pred_clses (B,3,4,32,32) f32
  const float* pb = (const float*)d_in[1];  // pred_boxes (B,3,4,32,32) f32
  const int*   tc = (const int*)d_in[2];    // targ_clses (B,4,32,32) i32
  const float* tb = (const float*)d_in[3];  // targ_boxes (B,4,32,32,3) f32
  int* out = (int*)d_out;                   // (B, C-1, 1, 3) int32 counts

  char* ws = (char*)d_ws;
  size_t off = 0;
  auto alloc = [&](size_t bytes) -> void* {
    void* p = ws + off;
    off += (bytes + 255) & ~(size_t)255;
    return p;
  };
  int*    Mcnt      = (int*)alloc(4 * 4);
  float4* posG      = (float4*)alloc((size_t)4 * N_ * 16);
  u16*    slotG     = (u16*)alloc((size_t)4 * N_ * 2);
  float4* sp4       = (float4*)alloc((size_t)4 * MMAX_ * 16);
  int*    deg       = (int*)alloc((size_t)4 * MMAX_ * 4);
  u16*    predL     = (u16*)alloc((size_t)4 * MMAX_ * KCAP_ * 2);
  float4* aliveList = (float4*)alloc((size_t)4 * MMAX_ * 16);
  int*    Acnt      = (int*)alloc(4 * 4);

  k_compact<<<4, 1024, 0, stream>>>(pc, pb, Mcnt, posG, slotG, sp4);
  k_adj<<<(4 * N_) / 256, 256, 0, stream>>>(posG, slotG, deg, predL);
  k_nms<<<4, 1024, 0, stream>>>(Mcnt, deg, predL, sp4, aliveList, Acnt, out);
  k_match<<<4 * 16, 256, 0, stream>>>(Acnt, aliveList, tc, tb, out);
}

// Round 8
// 106.416 us; speedup vs baseline: 1.6319x; 1.6319x over previous
//
#include <hip/hip_runtime.h>
#include <cstdint>
#include <cstddef>

typedef unsigned long long u64;
typedef unsigned int u32;
typedef unsigned short u16;

#define N_ 4096
#define MMAX_ 2048   // max candidates per (b,c) pair; actual ~1365
#define KCAP_ 32     // pred-list cap; geometric ball bound => max deg ~27
#define SENT_ 2048   // sentinel pred index -> always-dead byte slot

__device__ __forceinline__ float sigf(float x) { return 1.0f / (1.0f + expf(-x)); }

// any-of-4 alive check; w? are u32s holding two u16 indices each (constant reg idx)
#define ANY4(arr, wa, wb) \
  ((int)((arr)[(wa) & 0xFFFFu] | (arr)[(wa) >> 16] | \
         (arr)[(wb) & 0xFFFFu] | (arr)[(wb) >> 16]))
// degree-bounded group scan over reg-resident pred list (groups of 4, sentinel-padded)
#define GRPSCAN(arr, dw, dg, outAny) do { \
  outAny = ANY4(arr, dw[0], dw[1]); \
  if ((dg) > 4) { outAny |= ANY4(arr, dw[2], dw[3]); \
  if ((dg) > 8) { outAny |= ANY4(arr, dw[4], dw[5]); \
  if ((dg) > 12) { outAny |= ANY4(arr, dw[6], dw[7]); \
  if ((dg) > 16) { outAny |= ANY4(arr, dw[8], dw[9]); \
  if ((dg) > 20) { outAny |= ANY4(arr, dw[10], dw[11]); \
  if ((dg) > 24) { outAny |= ANY4(arr, dw[12], dw[13]); \
  if ((dg) > 28) { outAny |= ANY4(arr, dw[14], dw[15]); }}}}}}} \
} while (0)

// ---------------- K1: compact + dense lattice maps ----------------------------
// One block per (b,c) pair. Writes: slot-indexed sp4[slot]={x,y,z,bitcast(n)},
// dense posG[n]={x,y,z,bitcast(okey)} (invalid -> 1e9, distance self-rejects),
// slotG[n], and initializes alivePosG[n] to dead (k_nms scatters alive rows).
__global__ __launch_bounds__(1024) void k_compact(
    const float* __restrict__ pc, const float* __restrict__ pb,
    int* __restrict__ Mcnt, float4* __restrict__ posG, u16* __restrict__ slotG,
    float4* __restrict__ sp4, float4* __restrict__ alivePosG) {
  int pair = blockIdx.x, b = pair >> 1, c = (pair & 1) + 1;
  int tid = threadIdx.x, lane = tid & 63;
  __shared__ int cnt;
  if (tid == 0) cnt = 0;
  __syncthreads();
  const float* pcb = pc + (size_t)b * 3 * N_;
  const float* pbb = pb + (size_t)b * 3 * N_;
  for (int base = 0; base < N_; base += 1024) {
    int n = base + tid;
    float v0 = pcb[n], v1 = pcb[n + N_], v2 = pcb[n + 2 * N_];
    float cf = v0; int a = 0;
    if (v1 > cf) { cf = v1; a = 1; }
    if (v2 > cf) { cf = v2; a = 2; }
    bool valid = (a == c);
    u32 o = __float_as_uint(cf);
    o ^= (o >> 31) ? 0xFFFFFFFFu : 0x80000000u;   // ascending-orderable conf
    u64 ball = __ballot(valid);
    int wbase = 0;
    if (lane == 0 && ball) wbase = atomicAdd(&cnt, __popcll(ball));
    wbase = __shfl(wbase, 0);
    int p = wbase + __popcll(ball & ((1ull << lane) - 1ull));
    float4 dead; dead.x = 1e9f; dead.y = 1e9f; dead.z = 1e9f; dead.w = 0.f;
    alivePosG[pair * N_ + n] = dead;              // k_nms overwrites alive rows
    if (valid && p < MMAX_) {
      float d = (float)(n >> 10), h = (float)((n >> 5) & 31), w = (float)(n & 31);
      // (g+s)/dims*REAL == (g+s)*{0.75,0.78125,0.78125} bit-exactly (pow2 dims)
      float x = (d + sigf(pbb[n])) * 0.75f;
      float y = (h + sigf(pbb[n + N_])) * 0.78125f;
      float z = (w + sigf(pbb[n + 2 * N_])) * 0.78125f;
      float4 vg; vg.x = x; vg.y = y; vg.z = z; vg.w = __uint_as_float(o);
      posG[pair * N_ + n] = vg;
      slotG[pair * N_ + n] = (u16)p;
      float4 vs; vs.x = x; vs.y = y; vs.z = z; vs.w = __uint_as_float((u32)n);
      sp4[pair * MMAX_ + p] = vs;
    } else {
      posG[pair * N_ + n] = dead;
      slotG[pair * N_ + n] = (u16)0xFFFF;
    }
  }
  __syncthreads();
  if (tid == 0) {
    int M = cnt; if (M > MMAX_) M = MMAX_;
    Mcnt[pair] = M;
  }
}

// ---------------- K2: lattice-ball predecessor adjacency ----------------------
// One thread per anchor. Geometric pruning (offsets in open (0,1)):
//   cut=1.0 : two axes at |dcell|=2 give min d2 >= 1.17 > 1.0  -> 80-cell ball
//   cut=0.75: any axis at |dcell|=2 exceeds 0.75 strictly      -> 26-cell ball
// Independent coalesced 16B loads, fully unrolled -> pipelined, no LDS.
// pred(i,j): dist<cut && (okey_i > okey_j || (okey_i==okey_j && n_i < n_j))
// == "i earlier in ref's stable desc-conf sort" (key orientation, label-free).
template <int EXT>
__device__ __forceinline__ void adj_body(
    const float4* __restrict__ posG, const u16* __restrict__ slotG,
    int* __restrict__ deg, u16* __restrict__ predL, int pair, int n, int slot,
    float cut2) {
  float4 self = posG[pair * N_ + n];
  u32 okey = __float_as_uint(self.w);
  int d0 = n >> 10, h0 = (n >> 5) & 31, w0 = n & 31;
  u16* rowp = predL + (((size_t)pair * MMAX_ + slot) << 5);
  int cnt = 0;
  #pragma unroll
  for (int dd = -EXT; dd <= EXT; ++dd) {
    #pragma unroll
    for (int dh = -EXT; dh <= EXT; ++dh) {
      #pragma unroll
      for (int dw = -EXT; dw <= EXT; ++dw) {
        if (dd == 0 && dh == 0 && dw == 0) continue;
        // compile-time ball prune: at most one axis at |2|
        if ((dd * dd == 4) + (dh * dh == 4) + (dw * dw == 4) > 1) continue;
        int d2i = d0 + dd, h2i = h0 + dh, w2i = w0 + dw;
        if ((u32)d2i < 4u && (u32)h2i < 32u && (u32)w2i < 32u) {
          int n2 = (d2i << 10) | (h2i << 5) | w2i;
          float4 pn = posG[pair * N_ + n2];    // invalid -> 1e9 -> dist rejects
          float dx = pn.x - self.x, dy = pn.y - self.y, dz = pn.z - self.z;
          float dsq = dx * dx + dy * dy + dz * dz;
          u32 ok2 = __float_as_uint(pn.w);
          bool pred = (dsq < cut2) && (ok2 > okey || (ok2 == okey && n2 < n));
          if (pred) {                          // rare (~2 per row)
            u16 s2 = slotG[pair * N_ + n2];
            if (cnt < KCAP_) rowp[cnt] = s2;
            cnt++;
          }
        }
      }
    }
  }
  if (cnt > KCAP_) cnt = KCAP_;
  deg[pair * MMAX_ + slot] = cnt;
  int pad = (cnt + 3) & ~3;                    // pad group-of-4 with sentinel
  for (int s = cnt; s < pad; ++s) rowp[s] = (u16)SENT_;
}

__global__ __launch_bounds__(256) void k_adj(
    const float4* __restrict__ posG, const u16* __restrict__ slotG,
    int* __restrict__ deg, u16* __restrict__ predL) {
  int idx = blockIdx.x * 256 + threadIdx.x;   // 0..16383
  int pair = idx >> 12, n = idx & (N_ - 1);
  int slot = slotG[pair * N_ + n];
  if (slot == 0xFFFF) return;
  if (pair & 1) adj_body<1>(posG, slotG, deg, predL, pair, n, slot, 0.5625f);
  else          adj_body<2>(posG, slotG, deg, predL, pair, n, slot, 1.0f);
}

// ---------------- K3: byte-array LDS matrix-NMS fixpoint ----------------------
// Per-iteration exactly the ref update:
//   free_i  = alive_i && no alive conflicting predecessor
//   alive'_j = alive_j && no free conflicting predecessor
// Monotone => early break at fixpoint exact; capped at ref's 32 iters.
// Epilogue scatters alive positions to the dense per-anchor map (n from sp4.w).
__global__ __launch_bounds__(1024) void k_nms(
    const int* __restrict__ Mcnt, const int* __restrict__ deg,
    const u16* __restrict__ predL, const float4* __restrict__ sp4,
    float4* __restrict__ alivePosG, int* __restrict__ out) {
  int pair = blockIdx.x;
  int tid = threadIdx.x;
  int M = Mcnt[pair];
  __shared__ unsigned char aliveB[2064];  // [2048] = sentinel slot, always 0
  __shared__ unsigned char freeB[2064];
  __shared__ int flag[2], acnt;
  int r0 = tid, r1 = tid + 1024;
  int dg0 = deg[pair * MMAX_ + r0];       // used only when r0 < M (else garbage, unused)
  int dg1 = deg[pair * MMAX_ + r1];
  u32 dw0[16], dw1[16];
  {
    const uint4* p0 = (const uint4*)(predL + (((size_t)pair * MMAX_ + r0) << 5));
    const uint4* p1 = (const uint4*)(predL + (((size_t)pair * MMAX_ + r1) << 5));
    #pragma unroll
    for (int q = 0; q < 4; ++q) {
      uint4 t0 = p0[q];
      dw0[4 * q] = t0.x; dw0[4 * q + 1] = t0.y; dw0[4 * q + 2] = t0.z; dw0[4 * q + 3] = t0.w;
      uint4 t1 = p1[q];
      dw1[4 * q] = t1.x; dw1[4 * q + 1] = t1.y; dw1[4 * q + 2] = t1.z; dw1[4 * q + 3] = t1.w;
    }
  }
  bool a0 = (r0 < M), a1 = (r1 < M);
  aliveB[r0] = a0; aliveB[r1] = a1;
  freeB[r0] = 0; freeB[r1] = 0;
  if (tid < 16) { aliveB[2048 + tid] = 0; freeB[2048 + tid] = 0; }
  if (tid == 0) { flag[0] = 0; flag[1] = 0; acnt = 0; }
  __syncthreads();

  for (int iter = 0; iter < 32; ++iter) {
    if (tid == 0) flag[(iter + 1) & 1] = 0;  // reset NEXT flag (barriers order it)
    // ---- stage 1: free = alive && all preds dead
    bool fr0 = a0, fr1 = a1;
    if (a0 && dg0) { int any; GRPSCAN(aliveB, dw0, dg0, any); fr0 = (any == 0); }
    if (a1 && dg1) { int any; GRPSCAN(aliveB, dw1, dg1, any); fr1 = (any == 0); }
    freeB[r0] = fr0; freeB[r1] = fr1;
    __syncthreads();
    // ---- stage 2: alive' = alive && no free pred (monotone: only 1->0)
    int lch = 0;
    if (a0 && dg0) { int any; GRPSCAN(freeB, dw0, dg0, any); if (any) { a0 = false; aliveB[r0] = 0; lch = 1; } }
    if (a1 && dg1) { int any; GRPSCAN(freeB, dw1, dg1, any); if (any) { a1 = false; aliveB[r1] = 0; lch = 1; } }
    if (lch) flag[iter & 1] = 1;
    __syncthreads();
    if (!flag[iter & 1]) break;  // fixpoint: remaining ref iterations are no-ops
  }

  // scatter alive positions to dense anchor map + count
  if (a0) {
    float4 v = sp4[pair * MMAX_ + r0];
    alivePosG[pair * N_ + (int)__float_as_uint(v.w)] = v;
  }
  if (a1) {
    float4 v = sp4[pair * MMAX_ + r1];
    alivePosG[pair * N_ + (int)__float_as_uint(v.w)] = v;
  }
  {
    u64 ball = __ballot(a0);
    if ((tid & 63) == 0 && ball) atomicAdd(&acnt, __popcll(ball));
  }
  {
    u64 ball = __ballot(a1);
    if ((tid & 63) == 0 && ball) atomicAdd(&acnt, __popcll(ball));
  }
  __syncthreads();
  if (tid == 0) {
    int A = acnt;
    out[pair * 3 + 0] = 0;   // tp  (K4 adds)
    out[pair * 3 + 1] = A;   // fp = A - tp (K4 subtracts)
    out[pair * 3 + 2] = 0;   // fn = t_cls - tp (K4 adds/subtracts)
  }
}

// ---------------- K4: lattice-ball target matching ----------------------------
// One thread per anchor; a matching alive pred lies within the same +/-2 ball
// (target offset in [0,1), pred offset in (0,1): identical bound as k_adj,
// but INCLUDING the center cell). O(81) independent coalesced loads, no LDS,
// no O(A) scan.
template <int EXT>
__device__ __forceinline__ int match_ball(
    const float4* __restrict__ alive, int n, float tx, float ty, float tz,
    float cut2) {
  int d0 = n >> 10, h0 = (n >> 5) & 31, w0 = n & 31;
  int m = 0;
  #pragma unroll
  for (int dd = -EXT; dd <= EXT; ++dd) {
    #pragma unroll
    for (int dh = -EXT; dh <= EXT; ++dh) {
      #pragma unroll
      for (int dw = -EXT; dw <= EXT; ++dw) {
        // compile-time ball prune: at most one axis at |2|
        if ((dd * dd == 4) + (dh * dh == 4) + (dw * dw == 4) > 1) continue;
        int d2i = d0 + dd, h2i = h0 + dh, w2i = w0 + dw;
        if ((u32)d2i < 4u && (u32)h2i < 32u && (u32)w2i < 32u) {
          int n2 = (d2i << 10) | (h2i << 5) | w2i;
          float4 p = alive[n2];               // dead -> 1e9 -> dist rejects
          float dx = p.x - tx, dy = p.y - ty, dz = p.z - tz;
          m |= (int)(dx * dx + dy * dy + dz * dz < cut2);
        }
      }
    }
  }
  return m;
}

__global__ __launch_bounds__(256) void k_match(
    const float4* __restrict__ alivePosG,
    const int* __restrict__ tcls, const float* __restrict__ tb,
    int* __restrict__ out) {
  int idx = blockIdx.x * 256 + threadIdx.x;   // 0..16383
  int pair = idx >> 12, n = idx & (N_ - 1);
  int b = pair >> 1, c = (pair & 1) + 1;
  float cut2 = (pair & 1) ? 0.5625f : 1.0f;
  __shared__ int s_tp, s_t;
  if (threadIdx.x == 0) { s_tp = 0; s_t = 0; }
  __syncthreads();
  int isC = (tcls[b * N_ + n] == c) ? 1 : 0;
  float d = (float)(n >> 10), h = (float)((n >> 5) & 31), w = (float)(n & 31);
  const float* tbp = tb + ((size_t)b * N_ + n) * 3;
  float tx = (d + tbp[0]) * 0.75f;
  float ty = (h + tbp[1]) * 0.78125f;
  float tz = (w + tbp[2]) * 0.78125f;
  const float4* alive = alivePosG + (size_t)pair * N_;
  int m;
  if (pair & 1) m = match_ball<1>(alive, n, tx, ty, tz, cut2);
  else          m = match_ball<2>(alive, n, tx, ty, tz, cut2);
  m &= isC;
  atomicAdd(&s_tp, m);
  atomicAdd(&s_t, isC);
  __syncthreads();
  if (threadIdx.x == 0) {
    atomicAdd(&out[pair * 3 + 0], s_tp);
    atomicAdd(&out[pair * 3 + 1], -s_tp);
    atomicAdd(&out[pair * 3 + 2], s_t - s_tp);
  }
}

// ------------------------------------------------------------------------------
extern "C" void kernel_launch(void* const* d_in, const int* in_sizes, int n_in,
                              void* d_out, int out_size, void* d_ws, size_t ws_size,
                              hipStream_t stream) {
  (void)in_sizes; (void)n_in; (void)out_size; (void)ws_size;
  const float* pc = (const float*)d_in[0];  // pred_clses (B,3,4,32,32) f32
  const float* pb = (const float*)d_in[1];  // pred_boxes (B,3,4,32,32) f32
  const int*   tc = (const int*)d_in[2];    // targ_clses (B,4,32,32) i32
  const float* tb = (const float*)d_in[3];  // targ_boxes (B,4,32,32,3) f32
  int* out = (int*)d_out;                   // (B, C-1, 1, 3) int32 counts

  char* ws = (char*)d_ws;
  size_t off = 0;
  auto alloc = [&](size_t bytes) -> void* {
    void* p = ws + off;
    off += (bytes + 255) & ~(size_t)255;
    return p;
  };
  int*    Mcnt      = (int*)alloc(4 * 4);
  float4* posG      = (float4*)alloc((size_t)4 * N_ * 16);
  u16*    slotG     = (u16*)alloc((size_t)4 * N_ * 2);
  float4* sp4       = (float4*)alloc((size_t)4 * MMAX_ * 16);
  int*    deg       = (int*)alloc((size_t)4 * MMAX_ * 4);
  u16*    predL     = (u16*)alloc((size_t)4 * MMAX_ * KCAP_ * 2);
  float4* alivePosG = (float4*)alloc((size_t)4 * N_ * 16);

  k_compact<<<4, 1024, 0, stream>>>(pc, pb, Mcnt, posG, slotG, sp4, alivePosG);
  k_adj<<<(4 * N_) / 256, 256, 0, stream>>>(posG, slotG, deg, predL);
  k_nms<<<4, 1024, 0, stream>>>(Mcnt, deg, predL, sp4, alivePosG, out);
  k_match<<<(4 * N_) / 256, 256, 0, stream>>>(alivePosG, tc, tb, out);
}